// Round 1
// baseline (6535.352 us; speedup 1.0000x reference)
//
#include <hip/hip_runtime.h>

// Problem constants
#define BATCH 256
#define SEQ   128
#define IDIM  1024     // 256 + 768
#define HDIM  1024
#define G3    3072     // 3*HDIM
#define MROWS 32768    // BATCH*SEQ

typedef __attribute__((ext_vector_type(8))) short bf16x8;
typedef __attribute__((ext_vector_type(4))) short s16x4;
typedef __attribute__((ext_vector_type(4))) float f32x4;

__device__ __forceinline__ short f2bf(float f) {
    union { float f; unsigned u; } x; x.f = f;
    unsigned r = x.u + 0x7fffu + ((x.u >> 16) & 1u);   // RNE
    return (short)(r >> 16);
}
__device__ __forceinline__ float bf2f(unsigned short u) {
    union { unsigned u; float f; } x; x.u = ((unsigned)u) << 16;
    return x.f;
}

// ---------------------------------------------------------------------------
// Kernel 1: convert W_ih and W_hh (f32, row-major (3072,1024)) to bf16.
// grid 6144 x 256 == 2 * 786432 float4-items exactly.
__global__ void cvt_w(const float* __restrict__ wih, const float* __restrict__ whh,
                      short* __restrict__ wihb, short* __restrict__ whhb) {
    int i = blockIdx.x * 256 + threadIdx.x;
    const float* s; short* d; int j;
    if (i < 786432) { s = wih; d = wihb; j = i; }
    else            { s = whh; d = whhb; j = i - 786432; }
    const float4 v = *((const float4*)s + j);
    s16x4 o;
    o[0] = f2bf(v.x); o[1] = f2bf(v.y); o[2] = f2bf(v.z); o[3] = f2bf(v.w);
    *(s16x4*)(d + (size_t)j * 4) = o;
}

// ---------------------------------------------------------------------------
// Kernel 2: x_proj = concat(base,visual) @ W_ih^T + b_ih, stored bf16 at
// [(k*256 + b)*3072 + n].  m97-style 128x128 tile, BK=64, 256 threads.
__global__ __launch_bounds__(256, 2) void gemm_xproj(
    const float* __restrict__ base, const float* __restrict__ vis,
    const short* __restrict__ wihb, const float* __restrict__ bih,
    short* __restrict__ xp)
{
    __shared__ short As[128 * 64];
    __shared__ short Bs[128 * 64];
    const int tid = threadIdx.x;
    const int bid = blockIdx.x;
    const int nt = bid % 24, mt = bid / 24;     // consecutive blocks share A rows
    const int m0 = mt * 128, n0 = nt * 128;
    const int lane = tid & 63, w = tid >> 6;
    const int wm = w >> 1, wn = w & 1;
    const int l15 = lane & 15, quad = lane >> 4;

    f32x4 acc[4][4];
#pragma unroll
    for (int i = 0; i < 4; ++i)
#pragma unroll
        for (int j = 0; j < 4; ++j) acc[i][j] = (f32x4){0.f, 0.f, 0.f, 0.f};

    const int arow = tid >> 3;          // 0..31
    const int acol8 = (tid & 7) * 8;    // 0..56

    for (int kt = 0; kt < 16; ++kt) {
        const int k0 = kt * 64;
        __syncthreads();   // protect LDS from previous iteration's reads
#pragma unroll
        for (int is = 0; is < 4; ++is) {
            const int row = is * 32 + arow;
            const int col = k0 + acol8;   // block-uniform predicate (64 | 256)
            const float* s = (col < 256)
                ? (base + (size_t)(m0 + row) * 256 + col)
                : (vis  + (size_t)(m0 + row) * 768 + (col - 256));
            const float4 v0 = *(const float4*)s;
            const float4 v1 = *(const float4*)(s + 4);
            bf16x8 pk;
            pk[0] = f2bf(v0.x); pk[1] = f2bf(v0.y); pk[2] = f2bf(v0.z); pk[3] = f2bf(v0.w);
            pk[4] = f2bf(v1.x); pk[5] = f2bf(v1.y); pk[6] = f2bf(v1.z); pk[7] = f2bf(v1.w);
            *(bf16x8*)&As[is * 2048 + tid * 8] = pk;
            __builtin_amdgcn_global_load_lds(
                (const __attribute__((address_space(1))) void*)(wihb + (size_t)(n0 + is * 32 + (tid >> 3)) * 1024 + k0 + (tid & 7) * 8),
                (__attribute__((address_space(3))) void*)&Bs[is * 2048 + tid * 8],
                16, 0, 0);
        }
        __syncthreads();
#pragma unroll
        for (int s2 = 0; s2 < 2; ++s2) {
            bf16x8 af[4], bf[4];
#pragma unroll
            for (int i = 0; i < 4; ++i)
                af[i] = *(const bf16x8*)&As[(wm * 64 + i * 16 + l15) * 64 + s2 * 32 + quad * 8];
#pragma unroll
            for (int j = 0; j < 4; ++j)
                bf[j] = *(const bf16x8*)&Bs[(wn * 64 + j * 16 + l15) * 64 + s2 * 32 + quad * 8];
#pragma unroll
            for (int i = 0; i < 4; ++i)
#pragma unroll
                for (int j = 0; j < 4; ++j)
                    acc[i][j] = __builtin_amdgcn_mfma_f32_16x16x32_bf16(af[i], bf[j], acc[i][j], 0, 0, 0);
        }
    }
    // epilogue: +b_ih, bf16, scatter to (k, b, n)
#pragma unroll
    for (int j = 0; j < 4; ++j) {
        const int gn = n0 + wn * 64 + j * 16 + l15;
        const float bv = bih[gn];
#pragma unroll
        for (int i = 0; i < 4; ++i) {
            const int gmb = m0 + wm * 64 + i * 16 + quad * 4;
#pragma unroll
            for (int r = 0; r < 4; ++r) {
                const int gm = gmb + r;
                const size_t off = ((size_t)(gm & 127) * 256 + (size_t)(gm >> 7)) * 3072 + gn;
                xp[off] = f2bf(acc[i][j][r] + bv);
            }
        }
    }
}

// ---------------------------------------------------------------------------
// Kernel 3: persistent GRU recurrence. 256 blocks (1/CU) x 256 threads.
// Block = (bt 0..7, ct 0..31): 32 batch rows x 32 h-cols (96 gate cols).
// Each wave holds its whole W_hh slice (48 frags, 192 VGPRs) for all steps.
__global__ __launch_bounds__(256, 1) void gru_rec(
    const short* __restrict__ xp, const short* __restrict__ whhb,
    const float* __restrict__ bhh, short* __restrict__ hbuf,   // 2 x 256*1024 bf16, buf0 zeroed
    float* __restrict__ out, unsigned* __restrict__ ctr)       // 8*128 counters, zeroed
{
    __shared__ float red[4 * 32 * 96];   // 49152 B split-K partials
    const int tid = threadIdx.x;
    const int bid = blockIdx.x;
    const int bt = bid >> 5;       // batch group 0..7
    const int ct = bid & 31;       // col block  0..31
    const int lane = tid & 63, w = tid >> 6;
    const int l15 = lane & 15, quad = lane >> 4;
    const int bm0 = bt * 32;
    const int kbase = w * 256 + quad * 8;   // this wave's K-chunk

    // persistent W_hh fragments: 6 n-tiles x 8 k-iters
    bf16x8 Bf[6][8];
#pragma unroll
    for (int g = 0; g < 6; ++g) {
        const size_t col = (size_t)((g >> 1) * 1024 + ct * 32 + (g & 1) * 16 + l15);
#pragma unroll
        for (int kk = 0; kk < 8; ++kk)
            Bf[g][kk] = *(const bf16x8*)(whhb + col * 1024 + kbase + kk * 32);
    }

    const int ecol = tid & 31;     // h-col within block
    const int erow0 = tid >> 5;    // 0..7; thread owns rows erow0 + 8j
    const float bh0 = bhh[ct * 32 + ecol];
    const float bh1 = bhh[1024 + ct * 32 + ecol];
    const float bh2 = bhh[2048 + ct * 32 + ecol];

    float hold[4] = {0.f, 0.f, 0.f, 0.f};
    unsigned short xcur[12], xnxt[12];
#pragma unroll
    for (int j = 0; j < 4; ++j) {
        const size_t rb = (size_t)(bm0 + erow0 + j * 8) * 3072 + ct * 32 + ecol;
        xcur[j * 3 + 0] = (unsigned short)xp[rb];
        xcur[j * 3 + 1] = (unsigned short)xp[rb + 1024];
        xcur[j * 3 + 2] = (unsigned short)xp[rb + 2048];
    }

    for (int step = 0; step < 128; ++step) {
        const short* __restrict__ hr_ = hbuf + (size_t)(step & 1) * (256 * 1024);
        short* __restrict__ hw_ = hbuf + (size_t)((step + 1) & 1) * (256 * 1024);

        f32x4 acc[2][6];
#pragma unroll
        for (int i = 0; i < 2; ++i)
#pragma unroll
            for (int g = 0; g < 6; ++g) acc[i][g] = (f32x4){0.f, 0.f, 0.f, 0.f};

#pragma unroll
        for (int kk = 0; kk < 8; ++kk) {
            const bf16x8 a0 = *(const bf16x8*)(hr_ + (size_t)(bm0 + l15) * 1024 + kbase + kk * 32);
            const bf16x8 a1 = *(const bf16x8*)(hr_ + (size_t)(bm0 + 16 + l15) * 1024 + kbase + kk * 32);
#pragma unroll
            for (int g = 0; g < 6; ++g) {
                acc[0][g] = __builtin_amdgcn_mfma_f32_16x16x32_bf16(a0, Bf[g][kk], acc[0][g], 0, 0, 0);
                acc[1][g] = __builtin_amdgcn_mfma_f32_16x16x32_bf16(a1, Bf[g][kk], acc[1][g], 0, 0, 0);
            }
        }
        // split-K partials -> LDS  (row = batch within block, col = gate 0..95)
#pragma unroll
        for (int i = 0; i < 2; ++i)
#pragma unroll
            for (int g = 0; g < 6; ++g) {
                const int c96 = (g >> 1) * 32 + (g & 1) * 16 + l15;
                const int rb = w * 32 + i * 16 + quad * 4;
#pragma unroll
                for (int r = 0; r < 4; ++r)
                    red[(rb + r) * 96 + c96] = acc[i][g][r];
            }
        // prefetch next step's x_proj while partials land
        if (step < 127) {
#pragma unroll
            for (int j = 0; j < 4; ++j) {
                const size_t rb = ((size_t)(step + 1) * 256 + bm0 + erow0 + j * 8) * 3072 + ct * 32 + ecol;
                xnxt[j * 3 + 0] = (unsigned short)xp[rb];
                xnxt[j * 3 + 1] = (unsigned short)xp[rb + 1024];
                xnxt[j * 3 + 2] = (unsigned short)xp[rb + 2048];
            }
        }
        __syncthreads();
        // reduce 4 partials + gates + state update (f32 master state in regs)
#pragma unroll
        for (int j = 0; j < 4; ++j) {
            const int row = erow0 + j * 8;
            float hr = bh0, hz = bh1, hn = bh2;
#pragma unroll
            for (int ww = 0; ww < 4; ++ww) {
                const int b2 = (ww * 32 + row) * 96;
                hr += red[b2 + ecol];
                hz += red[b2 + 32 + ecol];
                hn += red[b2 + 64 + ecol];
            }
            const float xr = bf2f(xcur[j * 3 + 0]);
            const float xz = bf2f(xcur[j * 3 + 1]);
            const float xn = bf2f(xcur[j * 3 + 2]);
            const float rg = 1.f / (1.f + __expf(-(xr + hr)));
            const float zg = 1.f / (1.f + __expf(-(xz + hz)));
            const float e2 = __expf(2.f * (xn + rg * hn));
            const float ng = 1.f - 2.f / (e2 + 1.f);   // tanh, overflow-safe
            const float hv = (1.f - zg) * ng + zg * hold[j];
            hold[j] = hv;
            hw_[(size_t)(bm0 + row) * 1024 + ct * 32 + ecol] = f2bf(hv);
        }
        if (step < 127) {
            __threadfence();                 // release h writes to device scope
            __syncthreads();
            if (tid == 0) {
                const int ci = bt * 128 + step;
                __hip_atomic_fetch_add(&ctr[ci], 1u, __ATOMIC_RELEASE, __HIP_MEMORY_SCOPE_AGENT);
                while (__hip_atomic_load(&ctr[ci], __ATOMIC_ACQUIRE, __HIP_MEMORY_SCOPE_AGENT) < 32u)
                    __builtin_amdgcn_s_sleep(2);
            }
            __syncthreads();
            __threadfence();                 // acquire: invalidate L1/L2 lines
#pragma unroll
            for (int q = 0; q < 12; ++q) xcur[q] = xnxt[q];
        }
    }
#pragma unroll
    for (int j = 0; j < 4; ++j)
        out[(size_t)(bm0 + erow0 + j * 8) * 1024 + ct * 32 + ecol] = hold[j];
}

// ---------------------------------------------------------------------------
extern "C" void kernel_launch(void* const* d_in, const int* in_sizes, int n_in,
                              void* d_out, int out_size, void* d_ws, size_t ws_size,
                              hipStream_t stream) {
    (void)in_sizes; (void)n_in; (void)out_size; (void)ws_size;
    const float* base = (const float*)d_in[0];
    const float* vis  = (const float*)d_in[1];
    const float* wih  = (const float*)d_in[2];
    const float* whh  = (const float*)d_in[3];
    const float* bih  = (const float*)d_in[4];
    const float* bhh  = (const float*)d_in[5];

    char* ws = (char*)d_ws;
    short*    xp   = (short*)(ws + 0);                    // 201326592 B
    short*    wihb = (short*)(ws + 201326592);            //   6291456 B
    short*    whhb = (short*)(ws + 207618048);            //   6291456 B
    short*    hbuf = (short*)(ws + 213909504);            //   1048576 B (ping-pong)
    unsigned* ctr  = (unsigned*)(ws + 214958080);         //      4096 B

    hipMemsetAsync(hbuf, 0, 1048576, stream);             // h0 = 0 (both buffers)
    hipMemsetAsync(ctr, 0, 4096, stream);                 // barrier counters

    cvt_w<<<dim3(6144), dim3(256), 0, stream>>>(wih, whh, wihb, whhb);
    gemm_xproj<<<dim3(6144), dim3(256), 0, stream>>>(base, vis, wihb, bih, xp);
    gru_rec<<<dim3(256), dim3(256), 0, stream>>>(xp, whhb, bhh, hbuf, (float*)d_out, ctr);
}

// Round 2
// 2010.422 us; speedup vs baseline: 3.2507x; 3.2507x over previous
//
#include <hip/hip_runtime.h>

// Problem constants
#define BATCH 256
#define SEQ   128
#define IDIM  1024     // 256 + 768
#define HDIM  1024
#define G3    3072     // 3*HDIM

typedef __attribute__((ext_vector_type(8))) short bf16x8;
typedef __attribute__((ext_vector_type(4))) short s16x4;
typedef __attribute__((ext_vector_type(4))) float f32x4;

__device__ __forceinline__ short f2bf(float f) {
    union { float f; unsigned u; } x; x.f = f;
    unsigned r = x.u + 0x7fffu + ((x.u >> 16) & 1u);   // RNE
    return (short)(r >> 16);
}
__device__ __forceinline__ float bf2f(unsigned short u) {
    union { unsigned u; float f; } x; x.u = ((unsigned)u) << 16;
    return x.f;
}

// LLC-coherent 2-byte store: write-through past L1/L2 to the (coherent)
// Infinity Cache. No buffer_wbl2 needed for cross-XCD visibility.
__device__ __forceinline__ void store_short_llc(short* p, short v) {
    asm volatile("global_store_short %0, %1, off sc0 sc1" :: "v"(p), "v"(v) : "memory");
}

// ---------------------------------------------------------------------------
// Kernel 1: convert W_ih and W_hh (f32, row-major (3072,1024)) to bf16.
__global__ void cvt_w(const float* __restrict__ wih, const float* __restrict__ whh,
                      short* __restrict__ wihb, short* __restrict__ whhb) {
    int i = blockIdx.x * 256 + threadIdx.x;
    const float* s; short* d; int j;
    if (i < 786432) { s = wih; d = wihb; j = i; }
    else            { s = whh; d = whhb; j = i - 786432; }
    const float4 v = *((const float4*)s + j);
    s16x4 o;
    o[0] = f2bf(v.x); o[1] = f2bf(v.y); o[2] = f2bf(v.z); o[3] = f2bf(v.w);
    *(s16x4*)(d + (size_t)j * 4) = o;
}

// ---------------------------------------------------------------------------
// Kernel 2: x_proj = concat(base,visual) @ W_ih^T + b_ih, stored bf16 at
// [(k*256 + b)*3072 + n].  m97-style 128x128 tile, BK=64, 256 threads.
__global__ __launch_bounds__(256, 2) void gemm_xproj(
    const float* __restrict__ base, const float* __restrict__ vis,
    const short* __restrict__ wihb, const float* __restrict__ bih,
    short* __restrict__ xp)
{
    __shared__ short As[128 * 64];
    __shared__ short Bs[128 * 64];
    const int tid = threadIdx.x;
    const int bid = blockIdx.x;
    const int nt = bid % 24, mt = bid / 24;
    const int m0 = mt * 128, n0 = nt * 128;
    const int lane = tid & 63, w = tid >> 6;
    const int wm = w >> 1, wn = w & 1;
    const int l15 = lane & 15, quad = lane >> 4;

    f32x4 acc[4][4];
#pragma unroll
    for (int i = 0; i < 4; ++i)
#pragma unroll
        for (int j = 0; j < 4; ++j) acc[i][j] = (f32x4){0.f, 0.f, 0.f, 0.f};

    const int arow = tid >> 3;
    const int acol8 = (tid & 7) * 8;

    for (int kt = 0; kt < 16; ++kt) {
        const int k0 = kt * 64;
        __syncthreads();
#pragma unroll
        for (int is = 0; is < 4; ++is) {
            const int row = is * 32 + arow;
            const int col = k0 + acol8;   // block-uniform predicate (64 | 256)
            const float* s = (col < 256)
                ? (base + (size_t)(m0 + row) * 256 + col)
                : (vis  + (size_t)(m0 + row) * 768 + (col - 256));
            const float4 v0 = *(const float4*)s;
            const float4 v1 = *(const float4*)(s + 4);
            bf16x8 pk;
            pk[0] = f2bf(v0.x); pk[1] = f2bf(v0.y); pk[2] = f2bf(v0.z); pk[3] = f2bf(v0.w);
            pk[4] = f2bf(v1.x); pk[5] = f2bf(v1.y); pk[6] = f2bf(v1.z); pk[7] = f2bf(v1.w);
            *(bf16x8*)&As[is * 2048 + tid * 8] = pk;
            __builtin_amdgcn_global_load_lds(
                (const __attribute__((address_space(1))) void*)(wihb + (size_t)(n0 + is * 32 + (tid >> 3)) * 1024 + k0 + (tid & 7) * 8),
                (__attribute__((address_space(3))) void*)&Bs[is * 2048 + tid * 8],
                16, 0, 0);
        }
        __syncthreads();
#pragma unroll
        for (int s2 = 0; s2 < 2; ++s2) {
            bf16x8 af[4], bf[4];
#pragma unroll
            for (int i = 0; i < 4; ++i)
                af[i] = *(const bf16x8*)&As[(wm * 64 + i * 16 + l15) * 64 + s2 * 32 + quad * 8];
#pragma unroll
            for (int j = 0; j < 4; ++j)
                bf[j] = *(const bf16x8*)&Bs[(wn * 64 + j * 16 + l15) * 64 + s2 * 32 + quad * 8];
#pragma unroll
            for (int i = 0; i < 4; ++i)
#pragma unroll
                for (int j = 0; j < 4; ++j)
                    acc[i][j] = __builtin_amdgcn_mfma_f32_16x16x32_bf16(af[i], bf[j], acc[i][j], 0, 0, 0);
        }
    }
#pragma unroll
    for (int j = 0; j < 4; ++j) {
        const int gn = n0 + wn * 64 + j * 16 + l15;
        const float bv = bih[gn];
#pragma unroll
        for (int i = 0; i < 4; ++i) {
            const int gmb = m0 + wm * 64 + i * 16 + quad * 4;
#pragma unroll
            for (int r = 0; r < 4; ++r) {
                const int gm = gmb + r;
                const size_t off = ((size_t)(gm & 127) * 256 + (size_t)(gm >> 7)) * 3072 + gn;
                xp[off] = f2bf(acc[i][j][r] + bv);
            }
        }
    }
}

// ---------------------------------------------------------------------------
// Kernel 3: persistent GRU recurrence. 256 blocks (1/CU) x 256 threads.
// Block = (bt 0..7, ct 0..31): 32 batch rows x 32 h-cols (96 gate cols).
// W_hh slice lives in registers for all 128 steps. Cross-block h exchange
// goes through the coherent LLC: write-through sc0sc1 stores, relaxed
// counter barrier, ONE buffer_inv per step (no wbl2 anywhere).
__global__ __launch_bounds__(256, 1) void gru_rec(
    const short* __restrict__ xp, const short* __restrict__ whhb,
    const float* __restrict__ bhh, short* __restrict__ hbuf,   // 2 x 256*1024 bf16, zeroed
    float* __restrict__ out, unsigned* __restrict__ ctr)       // 8*128 counters, zeroed
{
    __shared__ float red[4 * 32 * 96];   // 49152 B split-K partials
    const int tid = threadIdx.x;
    const int bid = blockIdx.x;
    const int bt = bid >> 5;       // batch group 0..7
    const int ct = bid & 31;       // col block  0..31
    const int lane = tid & 63, w = tid >> 6;
    const int l15 = lane & 15, quad = lane >> 4;
    const int bm0 = bt * 32;
    const int kbase = w * 256 + quad * 8;   // this wave's K-chunk

    // persistent W_hh fragments: 6 n-tiles x 8 k-iters (192 VGPRs)
    bf16x8 Bf[6][8];
#pragma unroll
    for (int g = 0; g < 6; ++g) {
        const size_t col = (size_t)((g >> 1) * 1024 + ct * 32 + (g & 1) * 16 + l15);
#pragma unroll
        for (int kk = 0; kk < 8; ++kk)
            Bf[g][kk] = *(const bf16x8*)(whhb + col * 1024 + kbase + kk * 32);
    }

    const int ecol = tid & 31;     // h-col within block
    const int erow0 = tid >> 5;    // 0..7; thread owns rows erow0 + 8j
    const float bh0 = bhh[ct * 32 + ecol];
    const float bh1 = bhh[1024 + ct * 32 + ecol];
    const float bh2 = bhh[2048 + ct * 32 + ecol];

    float hold[4] = {0.f, 0.f, 0.f, 0.f};
    unsigned short xcur[12], xnxt[12];
#pragma unroll
    for (int j = 0; j < 4; ++j) {
        const size_t rb = (size_t)(bm0 + erow0 + j * 8) * 3072 + ct * 32 + ecol;
        xcur[j * 3 + 0] = (unsigned short)xp[rb];
        xcur[j * 3 + 1] = (unsigned short)xp[rb + 1024];
        xcur[j * 3 + 2] = (unsigned short)xp[rb + 2048];
    }

    for (int step = 0; step < 128; ++step) {
        const short* __restrict__ hr_ = hbuf + (size_t)(step & 1) * (256 * 1024);
        short* __restrict__ hw_ = hbuf + (size_t)((step + 1) & 1) * (256 * 1024);

        f32x4 acc[2][6];
#pragma unroll
        for (int i = 0; i < 2; ++i)
#pragma unroll
            for (int g = 0; g < 6; ++g) acc[i][g] = (f32x4){0.f, 0.f, 0.f, 0.f};

#pragma unroll
        for (int kk = 0; kk < 8; ++kk) {
            const bf16x8 a0 = *(const bf16x8*)(hr_ + (size_t)(bm0 + l15) * 1024 + kbase + kk * 32);
            const bf16x8 a1 = *(const bf16x8*)(hr_ + (size_t)(bm0 + 16 + l15) * 1024 + kbase + kk * 32);
#pragma unroll
            for (int g = 0; g < 6; ++g) {
                acc[0][g] = __builtin_amdgcn_mfma_f32_16x16x32_bf16(a0, Bf[g][kk], acc[0][g], 0, 0, 0);
                acc[1][g] = __builtin_amdgcn_mfma_f32_16x16x32_bf16(a1, Bf[g][kk], acc[1][g], 0, 0, 0);
            }
        }
        // split-K partials -> LDS
#pragma unroll
        for (int i = 0; i < 2; ++i)
#pragma unroll
            for (int g = 0; g < 6; ++g) {
                const int c96 = (g >> 1) * 32 + (g & 1) * 16 + l15;
                const int rb = w * 32 + i * 16 + quad * 4;
#pragma unroll
                for (int r = 0; r < 4; ++r)
                    red[(rb + r) * 96 + c96] = acc[i][g][r];
            }
        // prefetch next step's x_proj (read-only data, cached path is fine)
        if (step < 127) {
#pragma unroll
            for (int j = 0; j < 4; ++j) {
                const size_t rb = ((size_t)(step + 1) * 256 + bm0 + erow0 + j * 8) * 3072 + ct * 32 + ecol;
                xnxt[j * 3 + 0] = (unsigned short)xp[rb];
                xnxt[j * 3 + 1] = (unsigned short)xp[rb + 1024];
                xnxt[j * 3 + 2] = (unsigned short)xp[rb + 2048];
            }
        }
        __syncthreads();
        // reduce 4 partials + gates + state update (f32 master state in regs)
#pragma unroll
        for (int j = 0; j < 4; ++j) {
            const int row = erow0 + j * 8;
            float hr = bh0, hz = bh1, hn = bh2;
#pragma unroll
            for (int ww = 0; ww < 4; ++ww) {
                const int b2 = (ww * 32 + row) * 96;
                hr += red[b2 + ecol];
                hz += red[b2 + 32 + ecol];
                hn += red[b2 + 64 + ecol];
            }
            const float xr = bf2f(xcur[j * 3 + 0]);
            const float xz = bf2f(xcur[j * 3 + 1]);
            const float xn = bf2f(xcur[j * 3 + 2]);
            const float rg = 1.f / (1.f + __expf(-(xr + hr)));
            const float zg = 1.f / (1.f + __expf(-(xz + hz)));
            const float e2 = __expf(2.f * (xn + rg * hn));
            const float ng = 1.f - 2.f / (e2 + 1.f);   // tanh, overflow-safe
            const float hv = (1.f - zg) * ng + zg * hold[j];
            hold[j] = hv;
            // write-through to coherent LLC — no cache flush needed later
            store_short_llc(&hw_[(size_t)(bm0 + row) * 1024 + ct * 32 + ecol], f2bf(hv));
        }
        if (step < 127) {
            // drain the sc0sc1 stores to the LLC, then relaxed counter barrier
            asm volatile("s_waitcnt vmcnt(0)" ::: "memory");
            __syncthreads();
            if (tid == 0) {
                const int ci = bt * 128 + step;
                __hip_atomic_fetch_add(&ctr[ci], 1u, __ATOMIC_RELAXED, __HIP_MEMORY_SCOPE_AGENT);
                while (__hip_atomic_load(&ctr[ci], __ATOMIC_RELAXED, __HIP_MEMORY_SCOPE_AGENT) < 32u)
                    __builtin_amdgcn_s_sleep(1);
            }
            __syncthreads();
            // drop stale clean L1/L2 lines for this step's h reads (tag-only op)
            asm volatile("buffer_inv sc0 sc1" ::: "memory");
#pragma unroll
            for (int q = 0; q < 12; ++q) xcur[q] = xnxt[q];
        }
    }
#pragma unroll
    for (int j = 0; j < 4; ++j)
        out[(size_t)(bm0 + erow0 + j * 8) * 1024 + ct * 32 + ecol] = hold[j];
}

// ---------------------------------------------------------------------------
extern "C" void kernel_launch(void* const* d_in, const int* in_sizes, int n_in,
                              void* d_out, int out_size, void* d_ws, size_t ws_size,
                              hipStream_t stream) {
    (void)in_sizes; (void)n_in; (void)out_size; (void)ws_size;
    const float* base = (const float*)d_in[0];
    const float* vis  = (const float*)d_in[1];
    const float* wih  = (const float*)d_in[2];
    const float* whh  = (const float*)d_in[3];
    const float* bih  = (const float*)d_in[4];
    const float* bhh  = (const float*)d_in[5];

    char* ws = (char*)d_ws;
    short*    xp   = (short*)(ws + 0);                    // 201326592 B
    short*    wihb = (short*)(ws + 201326592);            //   6291456 B
    short*    whhb = (short*)(ws + 207618048);            //   6291456 B
    short*    hbuf = (short*)(ws + 213909504);            //   1048576 B (ping-pong)
    unsigned* ctr  = (unsigned*)(ws + 214958080);         //      4096 B

    hipMemsetAsync(hbuf, 0, 1048576, stream);             // h0 = 0 (both buffers)
    hipMemsetAsync(ctr, 0, 4096, stream);                 // barrier counters

    cvt_w<<<dim3(6144), dim3(256), 0, stream>>>(wih, whh, wihb, whhb);
    gemm_xproj<<<dim3(6144), dim3(256), 0, stream>>>(base, vis, wihb, bih, xp);
    gru_rec<<<dim3(256), dim3(256), 0, stream>>>(xp, whhb, bhh, hbuf, (float*)d_out, ctr);
}

// Round 3
// 1286.986 us; speedup vs baseline: 5.0780x; 1.5621x over previous
//
#include <hip/hip_runtime.h>

// Problem constants
#define BATCH 256
#define SEQ   128
#define IDIM  1024     // 256 + 768
#define HDIM  1024
#define G3    3072     // 3*HDIM

typedef __attribute__((ext_vector_type(8))) short bf16x8;
typedef __attribute__((ext_vector_type(4))) short s16x4;
typedef __attribute__((ext_vector_type(4))) float f32x4;

__device__ __forceinline__ short f2bf(float f) {
    union { float f; unsigned u; } x; x.f = f;
    unsigned r = x.u + 0x7fffu + ((x.u >> 16) & 1u);   // RNE
    return (short)(r >> 16);
}
__device__ __forceinline__ float bf2f(unsigned short u) {
    union { unsigned u; float f; } x; x.u = ((unsigned)u) << 16;
    return x.f;
}

// LLC-coherent stores: write-through past L1/L2 to the memory-side Infinity
// Cache (coherent across XCDs). No buffer_wbl2 / buffer_inv ever needed.
__device__ __forceinline__ void st_llc_b64(short* p, s16x4 v) {
    asm volatile("global_store_dwordx2 %0, %1, off sc0 sc1" :: "v"(p), "v"(v) : "memory");
}
// LLC-coherent 16B load, bypassing L1/L2 (issue only; waitcnt comes later,
// tied to the destinations so uses can't be hoisted).
#define LDH(dst, p, OFF) \
    asm volatile("global_load_dwordx4 %0, %1, off offset:" OFF " sc0 sc1" \
                 : "=v"(dst) : "v"(p))

// ---------------------------------------------------------------------------
// Kernel 1: convert W_ih and W_hh (f32, row-major (3072,1024)) to bf16.
__global__ void cvt_w(const float* __restrict__ wih, const float* __restrict__ whh,
                      short* __restrict__ wihb, short* __restrict__ whhb) {
    int i = blockIdx.x * 256 + threadIdx.x;
    const float* s; short* d; int j;
    if (i < 786432) { s = wih; d = wihb; j = i; }
    else            { s = whh; d = whhb; j = i - 786432; }
    const float4 v = *((const float4*)s + j);
    s16x4 o;
    o[0] = f2bf(v.x); o[1] = f2bf(v.y); o[2] = f2bf(v.z); o[3] = f2bf(v.w);
    *(s16x4*)(d + (size_t)j * 4) = o;
}

// ---------------------------------------------------------------------------
// Kernel 2: x_proj = concat(base,visual) @ W_ih^T + b_ih, stored bf16 at
// [(k*256 + b)*3072 + n].  m97-style 128x128 tile, BK=64, 256 threads.
__global__ __launch_bounds__(256, 2) void gemm_xproj(
    const float* __restrict__ base, const float* __restrict__ vis,
    const short* __restrict__ wihb, const float* __restrict__ bih,
    short* __restrict__ xp)
{
    __shared__ short As[128 * 64];
    __shared__ short Bs[128 * 64];
    const int tid = threadIdx.x;
    const int bid = blockIdx.x;
    const int nt = bid % 24, mt = bid / 24;
    const int m0 = mt * 128, n0 = nt * 128;
    const int lane = tid & 63, w = tid >> 6;
    const int wm = w >> 1, wn = w & 1;
    const int l15 = lane & 15, quad = lane >> 4;

    f32x4 acc[4][4];
#pragma unroll
    for (int i = 0; i < 4; ++i)
#pragma unroll
        for (int j = 0; j < 4; ++j) acc[i][j] = (f32x4){0.f, 0.f, 0.f, 0.f};

    const int arow = tid >> 3;
    const int acol8 = (tid & 7) * 8;

    for (int kt = 0; kt < 16; ++kt) {
        const int k0 = kt * 64;
        __syncthreads();
#pragma unroll
        for (int is = 0; is < 4; ++is) {
            const int row = is * 32 + arow;
            const int col = k0 + acol8;   // block-uniform predicate (64 | 256)
            const float* s = (col < 256)
                ? (base + (size_t)(m0 + row) * 256 + col)
                : (vis  + (size_t)(m0 + row) * 768 + (col - 256));
            const float4 v0 = *(const float4*)s;
            const float4 v1 = *(const float4*)(s + 4);
            bf16x8 pk;
            pk[0] = f2bf(v0.x); pk[1] = f2bf(v0.y); pk[2] = f2bf(v0.z); pk[3] = f2bf(v0.w);
            pk[4] = f2bf(v1.x); pk[5] = f2bf(v1.y); pk[6] = f2bf(v1.z); pk[7] = f2bf(v1.w);
            *(bf16x8*)&As[is * 2048 + tid * 8] = pk;
            __builtin_amdgcn_global_load_lds(
                (const __attribute__((address_space(1))) void*)(wihb + (size_t)(n0 + is * 32 + (tid >> 3)) * 1024 + k0 + (tid & 7) * 8),
                (__attribute__((address_space(3))) void*)&Bs[is * 2048 + tid * 8],
                16, 0, 0);
        }
        __syncthreads();
#pragma unroll
        for (int s2 = 0; s2 < 2; ++s2) {
            bf16x8 af[4], bf[4];
#pragma unroll
            for (int i = 0; i < 4; ++i)
                af[i] = *(const bf16x8*)&As[(wm * 64 + i * 16 + l15) * 64 + s2 * 32 + quad * 8];
#pragma unroll
            for (int j = 0; j < 4; ++j)
                bf[j] = *(const bf16x8*)&Bs[(wn * 64 + j * 16 + l15) * 64 + s2 * 32 + quad * 8];
#pragma unroll
            for (int i = 0; i < 4; ++i)
#pragma unroll
                for (int j = 0; j < 4; ++j)
                    acc[i][j] = __builtin_amdgcn_mfma_f32_16x16x32_bf16(af[i], bf[j], acc[i][j], 0, 0, 0);
        }
    }
#pragma unroll
    for (int j = 0; j < 4; ++j) {
        const int gn = n0 + wn * 64 + j * 16 + l15;
        const float bv = bih[gn];
#pragma unroll
        for (int i = 0; i < 4; ++i) {
            const int gmb = m0 + wm * 64 + i * 16 + quad * 4;
#pragma unroll
            for (int r = 0; r < 4; ++r) {
                const int gm = gmb + r;
                const size_t off = ((size_t)(gm & 127) * 256 + (size_t)(gm >> 7)) * 3072 + gn;
                xp[off] = f2bf(acc[i][j][r] + bv);
            }
        }
    }
}

// ---------------------------------------------------------------------------
// Kernel 3: persistent GRU recurrence. 256 blocks (1/CU) x 256 threads.
// Block = (bt 0..7, ct 0..31): 32 batch rows x 32 h-cols (96 gate cols).
// W_hh slice lives in registers for all 128 steps. Cross-block h exchange
// goes entirely through the coherent LLC: sc0sc1 write-through stores,
// sc0sc1 bypass loads, relaxed counter barrier. ZERO cache flush/inv ops.
__global__ __launch_bounds__(256, 1) void gru_rec(
    const short* __restrict__ xp, const short* __restrict__ whhb,
    const float* __restrict__ bhh, short* __restrict__ hbuf,   // 2 x 256*1024 bf16, zeroed
    float* __restrict__ out, unsigned* __restrict__ ctr)       // 8*128 counters, zeroed
{
    __shared__ float red[4 * 32 * 96];   // 49152 B split-K partials
    const int tid = threadIdx.x;
    const int bid = blockIdx.x;
    const int bt = bid >> 5;       // batch group 0..7
    const int ct = bid & 31;       // col block  0..31
    const int lane = tid & 63, w = tid >> 6;
    const int l15 = lane & 15, quad = lane >> 4;
    const int bm0 = bt * 32;
    const int kbase = w * 256 + quad * 8;   // this wave's K-chunk

    // persistent W_hh fragments: 6 n-tiles x 8 k-iters (192 VGPRs)
    bf16x8 Bf[6][8];
#pragma unroll
    for (int g = 0; g < 6; ++g) {
        const size_t col = (size_t)((g >> 1) * 1024 + ct * 32 + (g & 1) * 16 + l15);
#pragma unroll
        for (int kk = 0; kk < 8; ++kk)
            Bf[g][kk] = *(const bf16x8*)(whhb + col * 1024 + kbase + kk * 32);
    }

    // epilogue ownership: 1 row x 4 consecutive cols per thread
    const int er = tid >> 3;             // row within group, 0..31
    const int ec0 = (tid & 7) * 4;       // first col, 0..28
    const f32x4 bhr = *(const f32x4*)(bhh + ct * 32 + ec0);
    const f32x4 bhz = *(const f32x4*)(bhh + 1024 + ct * 32 + ec0);
    const f32x4 bhn = *(const f32x4*)(bhh + 2048 + ct * 32 + ec0);

    float hold[4] = {0.f, 0.f, 0.f, 0.f};
    s16x4 xc[3], xn_[3];
    {
        const size_t rb = (size_t)(bm0 + er) * 3072 + ct * 32 + ec0;
#pragma unroll
        for (int g = 0; g < 3; ++g) xc[g] = *(const s16x4*)(xp + rb + g * 1024);
    }

    for (int step = 0; step < 128; ++step) {
        const short* hr_ = hbuf + (size_t)(step & 1) * (256 * 1024);
        short* hw_ = hbuf + (size_t)((step + 1) & 1) * (256 * 1024);

        // --- h loads: 16 LLC-bypass b128 loads, then one tied waitcnt ---
        bf16x8 A0[8], A1[8];
        const short* p0 = hr_ + (size_t)(bm0 + l15) * 1024 + kbase;
        const short* p1 = p0 + 16 * 1024;
        LDH(A0[0], p0, "0");   LDH(A0[1], p0, "64");  LDH(A0[2], p0, "128"); LDH(A0[3], p0, "192");
        LDH(A0[4], p0, "256"); LDH(A0[5], p0, "320"); LDH(A0[6], p0, "384"); LDH(A0[7], p0, "448");
        LDH(A1[0], p1, "0");   LDH(A1[1], p1, "64");  LDH(A1[2], p1, "128"); LDH(A1[3], p1, "192");
        LDH(A1[4], p1, "256"); LDH(A1[5], p1, "320"); LDH(A1[6], p1, "384"); LDH(A1[7], p1, "448");
        asm volatile("s_waitcnt vmcnt(0)"
            : "+v"(A0[0]), "+v"(A0[1]), "+v"(A0[2]), "+v"(A0[3]),
              "+v"(A0[4]), "+v"(A0[5]), "+v"(A0[6]), "+v"(A0[7]),
              "+v"(A1[0]), "+v"(A1[1]), "+v"(A1[2]), "+v"(A1[3]),
              "+v"(A1[4]), "+v"(A1[5]), "+v"(A1[6]), "+v"(A1[7])
            :: "memory");

        f32x4 acc[2][6];
#pragma unroll
        for (int i = 0; i < 2; ++i)
#pragma unroll
            for (int g = 0; g < 6; ++g) acc[i][g] = (f32x4){0.f, 0.f, 0.f, 0.f};

#pragma unroll
        for (int kk = 0; kk < 8; ++kk) {
#pragma unroll
            for (int g = 0; g < 6; ++g) {
                acc[0][g] = __builtin_amdgcn_mfma_f32_16x16x32_bf16(A0[kk], Bf[g][kk], acc[0][g], 0, 0, 0);
                acc[1][g] = __builtin_amdgcn_mfma_f32_16x16x32_bf16(A1[kk], Bf[g][kk], acc[1][g], 0, 0, 0);
            }
        }
        // split-K partials -> LDS
#pragma unroll
        for (int i = 0; i < 2; ++i)
#pragma unroll
            for (int g = 0; g < 6; ++g) {
                const int c96 = (g >> 1) * 32 + (g & 1) * 16 + l15;
                const int rb = w * 32 + i * 16 + quad * 4;
#pragma unroll
                for (int r = 0; r < 4; ++r)
                    red[(rb + r) * 96 + c96] = acc[i][g][r];
            }
        // prefetch next step's x_proj (read-only, cached path)
        if (step < 127) {
            const size_t rb = ((size_t)(step + 1) * 256 + bm0 + er) * 3072 + ct * 32 + ec0;
#pragma unroll
            for (int g = 0; g < 3; ++g) xn_[g] = *(const s16x4*)(xp + rb + g * 1024);
        }
        __syncthreads();
        // reduce 4 split-K partials (vectorized) + gates + state update
        f32x4 sr = bhr, sz = bhz, sn = bhn;
#pragma unroll
        for (int ww = 0; ww < 4; ++ww) {
            const float* rbp = &red[(ww * 32 + er) * 96];
            sr += *(const f32x4*)(rbp + ec0);
            sz += *(const f32x4*)(rbp + 32 + ec0);
            sn += *(const f32x4*)(rbp + 64 + ec0);
        }
        s16x4 hpk;
        float ov[4];
#pragma unroll
        for (int i = 0; i < 4; ++i) {
            const float xr = bf2f((unsigned short)xc[0][i]);
            const float xz = bf2f((unsigned short)xc[1][i]);
            const float xnv = bf2f((unsigned short)xc[2][i]);
            const float rg = 1.f / (1.f + __expf(-(xr + sr[i])));
            const float zg = 1.f / (1.f + __expf(-(xz + sz[i])));
            const float e2 = __expf(2.f * (xnv + rg * sn[i]));
            const float ng = 1.f - 2.f / (e2 + 1.f);   // tanh, overflow-safe
            const float hv = (1.f - zg) * ng + zg * hold[i];
            hold[i] = hv; ov[i] = hv;
            hpk[i] = f2bf(hv);
        }
        st_llc_b64(&hw_[(size_t)(bm0 + er) * 1024 + ct * 32 + ec0], hpk);
        (void)ov;
        if (step < 127) {
            asm volatile("s_waitcnt vmcnt(0)" ::: "memory");  // drain h stores to LLC
            __syncthreads();
            if (tid == 0) {
                const int ci = bt * 128 + step;
                __hip_atomic_fetch_add(&ctr[ci], 1u, __ATOMIC_RELAXED, __HIP_MEMORY_SCOPE_AGENT);
                while (__hip_atomic_load(&ctr[ci], __ATOMIC_RELAXED, __HIP_MEMORY_SCOPE_AGENT) < 32u)
                    __builtin_amdgcn_s_sleep(1);
            }
            __syncthreads();
#pragma unroll
            for (int g = 0; g < 3; ++g) xc[g] = xn_[g];
        }
    }
    float4 o4; o4.x = hold[0]; o4.y = hold[1]; o4.z = hold[2]; o4.w = hold[3];
    *(float4*)(out + (size_t)(bm0 + er) * 1024 + ct * 32 + ec0) = o4;
}

// ---------------------------------------------------------------------------
extern "C" void kernel_launch(void* const* d_in, const int* in_sizes, int n_in,
                              void* d_out, int out_size, void* d_ws, size_t ws_size,
                              hipStream_t stream) {
    (void)in_sizes; (void)n_in; (void)out_size; (void)ws_size;
    const float* base = (const float*)d_in[0];
    const float* vis  = (const float*)d_in[1];
    const float* wih  = (const float*)d_in[2];
    const float* whh  = (const float*)d_in[3];
    const float* bih  = (const float*)d_in[4];
    const float* bhh  = (const float*)d_in[5];

    char* ws = (char*)d_ws;
    short*    xp   = (short*)(ws + 0);                    // 201326592 B
    short*    wihb = (short*)(ws + 201326592);            //   6291456 B
    short*    whhb = (short*)(ws + 207618048);            //   6291456 B
    short*    hbuf = (short*)(ws + 213909504);            //   1048576 B (ping-pong)
    unsigned* ctr  = (unsigned*)(ws + 214958080);         //      4096 B

    hipMemsetAsync(hbuf, 0, 1048576, stream);             // h0 = 0 (both buffers)
    hipMemsetAsync(ctr, 0, 4096, stream);                 // barrier counters

    cvt_w<<<dim3(6144), dim3(256), 0, stream>>>(wih, whh, wihb, whhb);
    gemm_xproj<<<dim3(6144), dim3(256), 0, stream>>>(base, vis, wihb, bih, xp);
    gru_rec<<<dim3(256), dim3(256), 0, stream>>>(xp, whhb, bhh, hbuf, (float*)d_out, ctr);
}

// Round 5
// 1194.657 us; speedup vs baseline: 5.4705x; 1.0773x over previous
//
#include <hip/hip_runtime.h>

// Problem constants
#define BATCH 256
#define SEQ   128
#define IDIM  1024     // 256 + 768
#define HDIM  1024
#define G3    3072     // 3*HDIM
#define RS    100      // padded row stride (dwords) of split-K LDS buffer

typedef __attribute__((ext_vector_type(8))) short bf16x8;
typedef __attribute__((ext_vector_type(4))) short s16x4;
typedef __attribute__((ext_vector_type(4))) float f32x4;

__device__ __forceinline__ short f2bf(float f) {
    union { float f; unsigned u; } x; x.f = f;
    unsigned r = x.u + 0x7fffu + ((x.u >> 16) & 1u);   // RNE
    return (short)(r >> 16);
}
__device__ __forceinline__ float bf2f(unsigned short u) {
    union { unsigned u; float f; } x; x.u = ((unsigned)u) << 16;
    return x.f;
}

// LLC-coherent ops: write-through / bypass L1+L2, coherent at Infinity Cache.
__device__ __forceinline__ void st_llc_b64(short* p, s16x4 v) {
    asm volatile("global_store_dwordx2 %0, %1, off sc0 sc1" :: "v"(p), "v"(v) : "memory");
}
__device__ __forceinline__ void st_llc_b32(unsigned* p, unsigned v) {
    asm volatile("global_store_dword %0, %1, off sc0 sc1" :: "v"(p), "v"(v) : "memory");
}
#define LDH(dst, p, OFF) \
    asm volatile("global_load_dwordx4 %0, %1, off offset:" OFF " sc0 sc1" \
                 : "=v"(dst) : "v"(p))
#define LDX(dst, p) \
    asm volatile("global_load_dwordx2 %0, %1, off" : "=v"(dst) : "v"(p))

// ---------------------------------------------------------------------------
// Kernel 1: convert W_ih and W_hh (f32, row-major (3072,1024)) to bf16.
__global__ void cvt_w(const float* __restrict__ wih, const float* __restrict__ whh,
                      short* __restrict__ wihb, short* __restrict__ whhb) {
    int i = blockIdx.x * 256 + threadIdx.x;
    const float* s; short* d; int j;
    if (i < 786432) { s = wih; d = wihb; j = i; }
    else            { s = whh; d = whhb; j = i - 786432; }
    const float4 v = *((const float4*)s + j);
    s16x4 o;
    o[0] = f2bf(v.x); o[1] = f2bf(v.y); o[2] = f2bf(v.z); o[3] = f2bf(v.w);
    *(s16x4*)(d + (size_t)j * 4) = o;
}

// ---------------------------------------------------------------------------
// Kernel 2: x_proj = concat(base,visual) @ W_ih^T + b_ih, stored bf16 at
// [(k*256 + b)*3072 + n].  128x128 tile, BK=64, 256 threads.
// Epilogue staged through an LDS C-tile for fully-coalesced 16B stores.
__global__ __launch_bounds__(256, 2) void gemm_xproj(
    const float* __restrict__ base, const float* __restrict__ vis,
    const short* __restrict__ wihb, const float* __restrict__ bih,
    short* __restrict__ xp)
{
    __shared__ union {
        struct { short A[128 * 64]; short B[128 * 64]; } ab;
        short C[128 * 136];            // 136-short row stride (pad) for epilogue
    } sm;
    const int tid = threadIdx.x;
    const int bid = blockIdx.x;
    const int nt = bid % 24, mt = bid / 24;
    const int m0 = mt * 128, n0 = nt * 128;
    const int lane = tid & 63, w = tid >> 6;
    const int wm = w >> 1, wn = w & 1;
    const int l15 = lane & 15, quad = lane >> 4;

    f32x4 acc[4][4];
#pragma unroll
    for (int i = 0; i < 4; ++i)
#pragma unroll
        for (int j = 0; j < 4; ++j) acc[i][j] = (f32x4){0.f, 0.f, 0.f, 0.f};

    const int arow = tid >> 3;
    const int acol8 = (tid & 7) * 8;

    for (int kt = 0; kt < 16; ++kt) {
        const int k0 = kt * 64;
        __syncthreads();
#pragma unroll
        for (int is = 0; is < 4; ++is) {
            const int row = is * 32 + arow;
            const int col = k0 + acol8;   // block-uniform predicate (64 | 256)
            const float* s = (col < 256)
                ? (base + (size_t)(m0 + row) * 256 + col)
                : (vis  + (size_t)(m0 + row) * 768 + (col - 256));
            const float4 v0 = *(const float4*)s;
            const float4 v1 = *(const float4*)(s + 4);
            bf16x8 pk;
            pk[0] = f2bf(v0.x); pk[1] = f2bf(v0.y); pk[2] = f2bf(v0.z); pk[3] = f2bf(v0.w);
            pk[4] = f2bf(v1.x); pk[5] = f2bf(v1.y); pk[6] = f2bf(v1.z); pk[7] = f2bf(v1.w);
            *(bf16x8*)&sm.ab.A[is * 2048 + tid * 8] = pk;
            __builtin_amdgcn_global_load_lds(
                (const __attribute__((address_space(1))) void*)(wihb + (size_t)(n0 + is * 32 + (tid >> 3)) * 1024 + k0 + (tid & 7) * 8),
                (__attribute__((address_space(3))) void*)&sm.ab.B[is * 2048 + tid * 8],
                16, 0, 0);
        }
        __syncthreads();
#pragma unroll
        for (int s2 = 0; s2 < 2; ++s2) {
            bf16x8 af[4], bf[4];
#pragma unroll
            for (int i = 0; i < 4; ++i)
                af[i] = *(const bf16x8*)&sm.ab.A[(wm * 64 + i * 16 + l15) * 64 + s2 * 32 + quad * 8];
#pragma unroll
            for (int j = 0; j < 4; ++j)
                bf[j] = *(const bf16x8*)&sm.ab.B[(wn * 64 + j * 16 + l15) * 64 + s2 * 32 + quad * 8];
#pragma unroll
            for (int i = 0; i < 4; ++i)
#pragma unroll
                for (int j = 0; j < 4; ++j)
                    acc[i][j] = __builtin_amdgcn_mfma_f32_16x16x32_bf16(af[i], bf[j], acc[i][j], 0, 0, 0);
        }
    }
    __syncthreads();     // A/B dead; reuse as C-tile
#pragma unroll
    for (int j = 0; j < 4; ++j) {
        const int cn = wn * 64 + j * 16 + l15;
        const float bv = bih[n0 + cn];
#pragma unroll
        for (int i = 0; i < 4; ++i) {
            const int rb = wm * 64 + i * 16 + quad * 4;
#pragma unroll
            for (int r = 0; r < 4; ++r)
                sm.C[(rb + r) * 136 + cn] = f2bf(acc[i][j][r] + bv);
        }
    }
    __syncthreads();
    // cooperative coalesced store: thread -> (row, 64-col half), 8 x 16B
    {
        const int row = tid >> 1, c0 = (tid & 1) * 64;
        const int gm = m0 + row;
        short* dst = xp + ((size_t)(gm & 127) * 256 + (size_t)(gm >> 7)) * 3072 + n0 + c0;
        const short* src = &sm.C[row * 136 + c0];
#pragma unroll
        for (int c = 0; c < 64; c += 8)
            *(bf16x8*)(dst + c) = *(const bf16x8*)(src + c);
    }
}

// ---------------------------------------------------------------------------
// Kernel 3: persistent GRU recurrence. 256 blocks (1/CU) x 256 threads.
// Block = (bt 0..7, ct 0..31): 32 batch rows x 32 h-cols (96 gate cols).
// W_hh slice in registers for all 128 steps. h exchange through coherent LLC
// (sc0sc1 stores/loads). Sync = per-block flags packed in one 128B line per
// batch group, monotone step values, polled by all waves with one coalesced
// bypass load + ballot. ZERO cache flush/inv ops, ZERO same-address RMW.
// ALL async asm loads have their destinations tied to a s_waitcnt asm before
// first use (register-lifetime hazard — R4's NaN came from untied xn_).
__global__ __launch_bounds__(256, 1) void gru_rec(
    const short* __restrict__ xp, const short* __restrict__ whhb,
    const float* __restrict__ bhh, short* __restrict__ hbuf,   // 2 x 256*1024 bf16, zeroed
    float* __restrict__ out, unsigned* __restrict__ flags)     // 8*32 flags, zeroed
{
    __shared__ float red[128 * RS];   // 51200 B split-K partials, padded stride
    const int tid = threadIdx.x;
    const int bid = blockIdx.x;
    const int bt = bid >> 5;       // batch group 0..7
    const int ct = bid & 31;       // col block  0..31
    const int lane = tid & 63, w = tid >> 6;
    const int l15 = lane & 15, quad = lane >> 4;
    const int bm0 = bt * 32;
    const int kbase = w * 256 + quad * 8;   // this wave's K-chunk

    // persistent W_hh fragments: 6 n-tiles x 8 k-iters (192 VGPRs)
    bf16x8 Bf[6][8];
#pragma unroll
    for (int g = 0; g < 6; ++g) {
        const size_t col = (size_t)((g >> 1) * 1024 + ct * 32 + (g & 1) * 16 + l15);
#pragma unroll
        for (int kk = 0; kk < 8; ++kk)
            Bf[g][kk] = *(const bf16x8*)(whhb + col * 1024 + kbase + kk * 32);
    }

    // epilogue ownership: 1 row x 4 consecutive cols per thread
    const int er = tid >> 3;             // row within group, 0..31
    const int ec0 = (tid & 7) * 4;       // first col, 0..28
    const f32x4 bhr = *(const f32x4*)(bhh + ct * 32 + ec0);
    const f32x4 bhz = *(const f32x4*)(bhh + 1024 + ct * 32 + ec0);
    const f32x4 bhn = *(const f32x4*)(bhh + 2048 + ct * 32 + ec0);

    unsigned* const myflag = flags + bt * 32 + ct;
    const unsigned* const pollp = flags + bt * 32 + (lane & 31);

    float hold[4] = {0.f, 0.f, 0.f, 0.f};
    s16x4 xc[3], xn_[3];
    {
        const size_t rb = (size_t)(bm0 + er) * 3072 + ct * 32 + ec0;
#pragma unroll
        for (int g = 0; g < 3; ++g) xc[g] = *(const s16x4*)(xp + rb + g * 1024);
    }

    for (int step = 0; step < 128; ++step) {
        // --- wait for step's h (producers flagged `step`); step 0 pre-zeroed ---
        if (step > 0) {
            const unsigned tgt = (unsigned)step;
            unsigned fv;
            do {
                asm volatile("global_load_dword %0, %1, off sc0 sc1" : "=v"(fv) : "v"(pollp));
                asm volatile("s_waitcnt vmcnt(0)" : "+v"(fv) :: "memory");
            } while (__ballot(fv < tgt));
        }
        const short* hr_ = hbuf + (size_t)(step & 1) * (256 * 1024);
        short* hw_ = hbuf + (size_t)((step + 1) & 1) * (256 * 1024);

        // --- h loads: 16 LLC-bypass b128 loads, one tied waitcnt ---
        bf16x8 A0[8], A1[8];
        const short* p0 = hr_ + (size_t)(bm0 + l15) * 1024 + kbase;
        const short* p1 = p0 + 16 * 1024;
        LDH(A0[0], p0, "0");   LDH(A0[1], p0, "64");  LDH(A0[2], p0, "128"); LDH(A0[3], p0, "192");
        LDH(A0[4], p0, "256"); LDH(A0[5], p0, "320"); LDH(A0[6], p0, "384"); LDH(A0[7], p0, "448");
        LDH(A1[0], p1, "0");   LDH(A1[1], p1, "64");  LDH(A1[2], p1, "128"); LDH(A1[3], p1, "192");
        LDH(A1[4], p1, "256"); LDH(A1[5], p1, "320"); LDH(A1[6], p1, "384"); LDH(A1[7], p1, "448");
        asm volatile("s_waitcnt vmcnt(0)"
            : "+v"(A0[0]), "+v"(A0[1]), "+v"(A0[2]), "+v"(A0[3]),
              "+v"(A0[4]), "+v"(A0[5]), "+v"(A0[6]), "+v"(A0[7]),
              "+v"(A1[0]), "+v"(A1[1]), "+v"(A1[2]), "+v"(A1[3]),
              "+v"(A1[4]), "+v"(A1[5]), "+v"(A1[6]), "+v"(A1[7])
            :: "memory");
        // early xp prefetch for step+1: a full step of compute to hide HBM miss.
        // Destinations are tied to the store-drain waitcnt below before use.
        if (step < 127) {
            const short* rb = xp + ((size_t)(step + 1) * 256 + bm0 + er) * 3072 + ct * 32 + ec0;
            LDX(xn_[0], rb); LDX(xn_[1], rb + 1024); LDX(xn_[2], rb + 2048);
        }

        f32x4 acc[2][6];
#pragma unroll
        for (int i = 0; i < 2; ++i)
#pragma unroll
            for (int g = 0; g < 6; ++g) acc[i][g] = (f32x4){0.f, 0.f, 0.f, 0.f};
#pragma unroll
        for (int kk = 0; kk < 8; ++kk) {
#pragma unroll
            for (int g = 0; g < 6; ++g) {
                acc[0][g] = __builtin_amdgcn_mfma_f32_16x16x32_bf16(A0[kk], Bf[g][kk], acc[0][g], 0, 0, 0);
                acc[1][g] = __builtin_amdgcn_mfma_f32_16x16x32_bf16(A1[kk], Bf[g][kk], acc[1][g], 0, 0, 0);
            }
        }
        // split-K partials -> LDS (padded stride: 2-way max, conflict-free)
#pragma unroll
        for (int i = 0; i < 2; ++i)
#pragma unroll
            for (int g = 0; g < 6; ++g) {
                const int c96 = (g >> 1) * 32 + (g & 1) * 16 + l15;
                const int rb = w * 32 + i * 16 + quad * 4;
#pragma unroll
                for (int r = 0; r < 4; ++r)
                    red[(rb + r) * RS + c96] = acc[i][g][r];
            }
        __syncthreads();
        // reduce 4 split-K partials + gates + state update
        f32x4 sr = bhr, sz = bhz, sn = bhn;
#pragma unroll
        for (int ww = 0; ww < 4; ++ww) {
            const float* rbp = &red[(ww * 32 + er) * RS];
            sr += *(const f32x4*)(rbp + ec0);
            sz += *(const f32x4*)(rbp + 32 + ec0);
            sn += *(const f32x4*)(rbp + 64 + ec0);
        }
        s16x4 hpk;
#pragma unroll
        for (int i = 0; i < 4; ++i) {
            const float xr = bf2f((unsigned short)xc[0][i]);
            const float xz = bf2f((unsigned short)xc[1][i]);
            const float xnv = bf2f((unsigned short)xc[2][i]);
            const float rg = 1.f / (1.f + __expf(-(xr + sr[i])));
            const float zg = 1.f / (1.f + __expf(-(xz + sz[i])));
            const float e2 = __expf(2.f * (xnv + rg * sn[i]));
            const float ng = 1.f - 2.f / (e2 + 1.f);   // tanh, overflow-safe
            const float hv = (1.f - zg) * ng + zg * hold[i];
            hold[i] = hv;
            hpk[i] = f2bf(hv);
        }
        if (step < 127) {
            st_llc_b64(&hw_[(size_t)(bm0 + er) * 1024 + ct * 32 + ec0], hpk);
            // drain h store AND the xn_ prefetch; tying xn_ here (a) pins the
            // registers until the data has landed, (b) makes the xc copy below
            // data-dependent on the drain (cannot be hoisted).
            asm volatile("s_waitcnt vmcnt(0)"
                : "+v"(xn_[0]), "+v"(xn_[1]), "+v"(xn_[2]) :: "memory");
            __syncthreads();                                   // all waves drained
            if (tid == 0) st_llc_b32(myflag, (unsigned)(step + 1));
            xc[0] = xn_[0]; xc[1] = xn_[1]; xc[2] = xn_[2];
        } else {
            __syncthreads();   // uniformity on last step (cheap)
        }
    }
    float4 o4; o4.x = hold[0]; o4.y = hold[1]; o4.z = hold[2]; o4.w = hold[3];
    *(float4*)(out + (size_t)(bm0 + er) * 1024 + ct * 32 + ec0) = o4;
}

// ---------------------------------------------------------------------------
extern "C" void kernel_launch(void* const* d_in, const int* in_sizes, int n_in,
                              void* d_out, int out_size, void* d_ws, size_t ws_size,
                              hipStream_t stream) {
    (void)in_sizes; (void)n_in; (void)out_size; (void)ws_size;
    const float* base = (const float*)d_in[0];
    const float* vis  = (const float*)d_in[1];
    const float* wih  = (const float*)d_in[2];
    const float* whh  = (const float*)d_in[3];
    const float* bih  = (const float*)d_in[4];
    const float* bhh  = (const float*)d_in[5];

    char* ws = (char*)d_ws;
    short*    xp   = (short*)(ws + 0);                    // 201326592 B
    short*    wihb = (short*)(ws + 201326592);            //   6291456 B
    short*    whhb = (short*)(ws + 207618048);            //   6291456 B
    short*    hbuf = (short*)(ws + 213909504);            //   1048576 B (ping-pong)
    unsigned* flg  = (unsigned*)(ws + 214958080);         //      4096 B

    hipMemsetAsync(hbuf, 0, 1048576, stream);             // h0 = 0 (both buffers)
    hipMemsetAsync(flg, 0, 4096, stream);                 // flags

    cvt_w<<<dim3(6144), dim3(256), 0, stream>>>(wih, whh, wihb, whhb);
    gemm_xproj<<<dim3(6144), dim3(256), 0, stream>>>(base, vis, wihb, bih, xp);
    gru_rec<<<dim3(256), dim3(256), 0, stream>>>(xp, whhb, bhh, hbuf, (float*)d_out, flg);
}